// Round 6
// baseline (198.817 us; speedup 1.0000x reference)
//
#include <hip/hip_runtime.h>
#include <hip/hip_bf16.h>

// GATLayer, scalar attention => uniform 1/deg over DISTINCT neighbors.
//   out[n, h*D+d] = sum_k W[h,d,k] * agg_x[n,k]
//   agg_x[n,:]    = mean_{j in distinct nbr(n)} x[j,:]  (mean over all N if deg==0)
// 2 launches: init (zero + cvtW) -> fused (scatter | bar | aggregate | bar | GEMM)
// with a hand-rolled grid barrier (all 512 blocks resident by construction).

constexpr int NN = 4096;          // nodes
constexpr int DD = 256;           // channels
constexpr int EE = 131072;        // edges
constexpr int MW = NN / 32;       // 128 mask words per row
constexpr int NOUT = 2048;        // H*D
constexpr int NB = 512;           // blocks: 2/CU x 256 CU -> all resident
constexpr int NT = 256;

// ws layout (16B-aligned slots): mask | colsum | bar | aggb | lwb
constexpr size_t OFF_COLSUM = (size_t)NN * MW * 4;            // 2 MB
constexpr size_t OFF_BAR    = OFF_COLSUM + DD * 4;            // +1 KB
constexpr size_t OFF_AGGB   = OFF_BAR + 16;                   // +16 B
constexpr size_t OFF_LWB    = OFF_AGGB + (size_t)NN * DD * 2; // +2 MB
constexpr int ZERO_F4 = (int)(OFF_AGGB / 16);                 // zero mask+colsum+bar

typedef __attribute__((ext_vector_type(4))) float f32x4;
typedef __attribute__((ext_vector_type(8))) short s16x8;

__device__ inline short f2bf(float f) {
    __hip_bfloat16 h = __float2bfloat16(f);
    return *reinterpret_cast<short*>(&h);
}

// ---- launch 1: zero {mask, colsum, barrier}; convert W fp32->bf16 ----
__global__ __launch_bounds__(256) void init_k(const float* __restrict__ w,
                                              short* __restrict__ wb,
                                              float4* __restrict__ zbase) {
    int b = blockIdx.x, t = threadIdx.x;
    if (b < 513) {
        int idx = b * 256 + t;
        if (idx < ZERO_F4) zbase[idx] = make_float4(0.f, 0.f, 0.f, 0.f);
    } else {
        int i = (b - 513) * 256 + t;                 // 131072 float4 = whole W
        float4 v = reinterpret_cast<const float4*>(w)[i];
        short4 o;
        o.x = f2bf(v.x); o.y = f2bf(v.y); o.z = f2bf(v.z); o.w = f2bf(v.w);
        reinterpret_cast<short4*>(wb)[i] = o;
    }
}

// ---- grid barrier: monotonic arrival counter (re-zeroed by init_k each call) ----
__device__ inline void grid_bar(unsigned int* bar, unsigned int target) {
    __syncthreads();                       // all block stores issued & waited
    if (threadIdx.x == 0) {
        __threadfence();                   // release: writeback dirty lines
        __hip_atomic_fetch_add(bar, 1u, __ATOMIC_ACQ_REL, __HIP_MEMORY_SCOPE_AGENT);
        while (__hip_atomic_load(bar, __ATOMIC_ACQUIRE, __HIP_MEMORY_SCOPE_AGENT)
               < target)
            __builtin_amdgcn_s_sleep(2);
        __threadfence();                   // acquire: invalidate stale lines
    }
    __syncthreads();
}

// ---- launch 2: scatter+colsum | bar | aggregate | bar | MFMA GEMM ----
__global__ __launch_bounds__(NT, 2) void fused_k(
        const float* __restrict__ x, const int* __restrict__ ei, int stride,
        unsigned int* __restrict__ mask, float* __restrict__ colsum,
        unsigned int* __restrict__ bar,
        short* __restrict__ aggb, const short* __restrict__ wb,
        float* __restrict__ C) {
    const int bid = blockIdx.x;
    const int t = threadIdx.x;
    const int g = bid * NT + t;                      // 0 .. 131071

    // ---- stage B: edge scatter into bitmask; colsum of x (deg==0 fallback) ----
    {
        int u = ei[(size_t)g * stride];              // one edge per thread, exact
        int v = ei[((size_t)EE + g) * stride];
        atomicOr(&mask[(size_t)u * MW + (v >> 5)], 1u << (v & 31));
    }
    if (bid < 64) {                                  // 64 blocks x 64 rows
        int r0 = bid * 64;
        float acc = 0.f;
        for (int r = 0; r < 64; ++r) acc += x[(size_t)(r0 + r) * DD + t];
        atomicAdd(&colsum[t], acc);
    }
    grid_bar(bar, NB);

    // ---- stage C: neighbor mean, 8 rows per block ----
    __shared__ int nbr[NN];              // 16 KB
    __shared__ int cnt;
    __shared__ float part[4][DD];        // 4 KB
    const int slot = t >> 6;             // wave 0..3
    const int c4 = (t & 63) << 2;        // 4 ch/lane -> 64 lanes = full row
    const float4 z4 = make_float4(0.f, 0.f, 0.f, 0.f);
    for (int rr = 0; rr < 8; ++rr) {
        int i = bid * 8 + rr;
        if (t == 0) cnt = 0;
        __syncthreads();
        if (t < MW) {                    // compact bits -> index list
            unsigned int m = mask[(size_t)i * MW + t];
            while (m) {
                int b = __ffs(m) - 1;
                m &= m - 1;
                nbr[atomicAdd(&cnt, 1)] = t * 32 + b;
            }
        }
        __syncthreads();
        int deg = cnt;

        float4 acc = z4;
        for (int r0 = slot * 4; r0 < deg; r0 += 16) {   // 4 loads in flight/wave
            int nn[4];
            float4 v[4];
#pragma unroll
            for (int j = 0; j < 4; ++j)
                nn[j] = (r0 + j < deg) ? nbr[r0 + j] : nbr[r0];
#pragma unroll
            for (int j = 0; j < 4; ++j)
                v[j] = *reinterpret_cast<const float4*>(&x[(size_t)nn[j] * DD + c4]);
#pragma unroll
            for (int j = 0; j < 4; ++j)
                if (r0 + j < deg) {
                    acc.x += v[j].x; acc.y += v[j].y;
                    acc.z += v[j].z; acc.w += v[j].w;
                }
        }
        *reinterpret_cast<float4*>(&part[slot][c4]) = acc;
        __syncthreads();
        float s = part[0][t] + part[1][t] + part[2][t] + part[3][t];
        float res = (deg > 0) ? s * (1.f / (float)deg)
                              : colsum[t] * (1.f / (float)NN);
        aggb[(size_t)i * DD + t] = f2bf(res);
        __syncthreads();
    }
    grid_bar(bar, 2u * NB);

    // ---- stage D: MFMA GEMM  C[4096][2048] = aggb[4096][256] * wb[2048][256]^T ----
    // 128x128 tile per block (32 x 16 = 512 tiles), 4 waves (2x2), 64x64/wave.
    {
        const int lane = t & 63;
        const int wv = t >> 6;
        const int wr = wv >> 1, wc = wv & 1;
        const int m0 = (bid >> 4) * 128 + wr * 64;
        const int n0 = (bid & 15) * 128 + wc * 64;
        const int lr = lane & 15;
        const int lk = (lane >> 4) * 8;

        f32x4 acc[4][4] = {};
        for (int k0 = 0; k0 < DD; k0 += 32) {
            s16x8 a[4], b[4];
#pragma unroll
            for (int i = 0; i < 4; ++i)
                a[i] = *reinterpret_cast<const s16x8*>(
                    &aggb[(size_t)(m0 + i * 16 + lr) * DD + k0 + lk]);
#pragma unroll
            for (int j = 0; j < 4; ++j)
                b[j] = *reinterpret_cast<const s16x8*>(
                    &wb[(size_t)(n0 + j * 16 + lr) * DD + k0 + lk]);
#pragma unroll
            for (int i = 0; i < 4; ++i)
#pragma unroll
                for (int j = 0; j < 4; ++j)
                    acc[i][j] = __builtin_amdgcn_mfma_f32_16x16x32_bf16(
                        a[i], b[j], acc[i][j], 0, 0, 0);
        }
        // C/D layout: col = lane&15, row = (lane>>4)*4 + reg
        const int crow = (lane >> 4) * 4;
        const int ccol = lane & 15;
#pragma unroll
        for (int i = 0; i < 4; ++i)
#pragma unroll
            for (int j = 0; j < 4; ++j)
#pragma unroll
                for (int r = 0; r < 4; ++r)
                    C[(size_t)(m0 + i * 16 + crow + r) * NOUT + n0 + j * 16 + ccol]
                        = acc[i][j][r];
    }
}

extern "C" void kernel_launch(void* const* d_in, const int* in_sizes, int n_in,
                              void* d_out, int out_size, void* d_ws, size_t ws_size,
                              hipStream_t stream) {
    const float* x  = (const float*)d_in[0];
    const float* lw = (const float*)d_in[1];   // [H][D][D] == [2048][256] row-major
    const int*   ei = (const int*)d_in[4];
    float* out = (float*)d_out;

    char* ws = (char*)d_ws;
    unsigned int* mask   = (unsigned int*)ws;
    float*        colsum = (float*)(ws + OFF_COLSUM);
    unsigned int* bar    = (unsigned int*)(ws + OFF_BAR);
    short*        aggb   = (short*)(ws + OFF_AGGB);
    short*        lwb    = (short*)(ws + OFF_LWB);

    // int64 edge_index delivered as int32 (2E elements) vs raw int64 (low words)
    int stride = (in_sizes[4] == 2 * EE) ? 1 : 2;

    init_k<<<513 + 512, 256, 0, stream>>>(lw, lwb, (float4*)ws);
    fused_k<<<NB, NT, 0, stream>>>(x, ei, stride, mask, colsum, bar, aggb, lwb, out);
}

// Round 7
// 63.741 us; speedup vs baseline: 3.1191x; 3.1191x over previous
//
#include <hip/hip_runtime.h>
#include <hip/hip_bf16.h>

// GATLayer, scalar attention => uniform 1/deg over DISTINCT neighbors.
//   out[n, h*D+d] = sum_k W[h,d,k] * agg_x[n,k]
//   agg_x[n,:]    = mean_{j in distinct nbr(n)} x[j,:]  (mean over all N if deg==0)
// 3 launches, no grid barrier: aggregate+GEMM fused block-locally (a block's
// 16-row C panel only needs agg for its own 16 rows -> agg stays in LDS).

constexpr int NN = 4096;          // nodes
constexpr int DD = 256;           // channels
constexpr int EE = 131072;        // edges
constexpr int MW = NN / 32;       // 128 mask words per row
constexpr int NOUT = 2048;        // H*D
constexpr int RPB = 16;           // rows (nodes) per mega block
constexpr int NB3 = NN / RPB;     // 256 mega blocks
constexpr int LCAP = 128;         // neighbor-list cap (deg ~ Poisson(32))

// ws layout: mask (2 MB) | colsum (1 KB) | lwb (1 MB bf16)
constexpr size_t OFF_COLSUM = (size_t)NN * MW * 4;            // 2 MB
constexpr size_t OFF_LWB    = OFF_COLSUM + DD * 4;            // +1 KB (16B aligned)
constexpr int ZERO_F4 = (int)(OFF_LWB / 16);                  // zero mask+colsum

typedef __attribute__((ext_vector_type(4))) float f32x4;
typedef __attribute__((ext_vector_type(8))) short s16x8;

__device__ inline short f2bf(float f) {
    __hip_bfloat16 h = __float2bfloat16(f);
    return *reinterpret_cast<short*>(&h);
}

// ---- launch 1: zero {mask, colsum}; convert W fp32->bf16 ----
__global__ __launch_bounds__(256) void init_k(const float* __restrict__ w,
                                              short* __restrict__ wb,
                                              float4* __restrict__ zbase) {
    int b = blockIdx.x, t = threadIdx.x;
    if (b < 513) {
        int idx = b * 256 + t;
        if (idx < ZERO_F4) zbase[idx] = make_float4(0.f, 0.f, 0.f, 0.f);
    } else {
        int i = (b - 513) * 256 + t;                 // 131072 float4 = whole W
        float4 v = reinterpret_cast<const float4*>(w)[i];
        short4 o;
        o.x = f2bf(v.x); o.y = f2bf(v.y); o.z = f2bf(v.z); o.w = f2bf(v.w);
        reinterpret_cast<short4*>(wb)[i] = o;
    }
}

// ---- launch 2: edge scatter into bitmask; colsum of x (deg==0 fallback) ----
__global__ __launch_bounds__(256) void edges_colsum_k(
        const int* __restrict__ ei, int stride, unsigned int* __restrict__ mask,
        const float* __restrict__ x, float* __restrict__ colsum) {
    int b = blockIdx.x, t = threadIdx.x;
    if (b < 512) {                                   // 512*256 = 131072 edges
        int e = b * 256 + t;
        int u = ei[(size_t)e * stride];              // src (row of adj)
        int v = ei[((size_t)EE + e) * stride];       // dst (col of adj)
        atomicOr(&mask[(size_t)u * MW + (v >> 5)], 1u << (v & 31));
    } else {                                         // 64 blocks x 64 rows
        int r0 = (b - 512) * 64;
        float acc = 0.f;
        for (int r = 0; r < 64; ++r) acc += x[(size_t)(r0 + r) * DD + t];
        atomicAdd(&colsum[t], acc);
    }
}

// ---- launch 3: per-16-row panel: compact -> gather-mean (LDS) -> MFMA GEMM ----
// 512 threads = 8 waves. C panel [16 x 2048] = agg[16 x 256] * W[2048 x 256]^T.
__global__ __launch_bounds__(512, 1) void mega_k(
        const float* __restrict__ x, const unsigned int* __restrict__ mask,
        const float* __restrict__ colsum, const short* __restrict__ wb,
        float* __restrict__ C) {
    __shared__ int nbr[RPB][LCAP];           // 8 KB
    __shared__ int cnt[RPB];
    __shared__ short aggl[RPB][DD + 8];      // bf16 agg, +8 pad: 2-way-free banks
    const int t = threadIdx.x;
    const int bid = blockIdx.x;
    const int row0 = bid * RPB;              // first node of this panel

    if (t < RPB) cnt[t] = 0;
    __syncthreads();

    // compaction: 16 rows x 32 threads x 4 words each
    {
        int r = t >> 5;                      // 0..15
        int w0 = (t & 31) * 4;
        const unsigned int* mr = &mask[(size_t)(row0 + r) * MW];
#pragma unroll
        for (int j = 0; j < 4; ++j) {
            unsigned int m = mr[w0 + j];
            while (m) {
                int b = __ffs(m) - 1;
                m &= m - 1;
                int idx = atomicAdd(&cnt[r], 1);
                if (idx < LCAP) nbr[r][idx] = (w0 + j) * 32 + b;
            }
        }
    }
    __syncthreads();

    // gather-mean: wave wv owns rows 2wv, 2wv+1; 64 lanes x float4 = full row
    {
        int wv = t >> 6;
        int c4 = (t & 63) << 2;
#pragma unroll
        for (int rr = 0; rr < 2; ++rr) {
            int r = wv * 2 + rr;
            int deg = min(cnt[r], LCAP);
            float4 acc = make_float4(0.f, 0.f, 0.f, 0.f);
            for (int q0 = 0; q0 < deg; q0 += 4) {    // 4 loads in flight
                int nn[4];
                float4 v[4];
#pragma unroll
                for (int j = 0; j < 4; ++j)
                    nn[j] = nbr[r][(q0 + j < deg) ? q0 + j : q0];
#pragma unroll
                for (int j = 0; j < 4; ++j)
                    v[j] = *reinterpret_cast<const float4*>(
                        &x[(size_t)nn[j] * DD + c4]);
#pragma unroll
                for (int j = 0; j < 4; ++j)
                    if (q0 + j < deg) {
                        acc.x += v[j].x; acc.y += v[j].y;
                        acc.z += v[j].z; acc.w += v[j].w;
                    }
            }
            float4 res;
            if (deg > 0) {
                float inv = 1.f / (float)deg;
                res = make_float4(acc.x * inv, acc.y * inv, acc.z * inv, acc.w * inv);
            } else {
                float4 cs = *reinterpret_cast<const float4*>(&colsum[c4]);
                float inv = 1.f / (float)NN;
                res = make_float4(cs.x * inv, cs.y * inv, cs.z * inv, cs.w * inv);
            }
            short4 o;
            o.x = f2bf(res.x); o.y = f2bf(res.y); o.z = f2bf(res.z); o.w = f2bf(res.w);
            *reinterpret_cast<short4*>(&aggl[r][c4]) = o;
        }
    }
    __syncthreads();

    // GEMM: 8 waves x 256 cols each (16 n-tiles of 16), M=16, K=256 (8 steps).
    {
        const int wv = t >> 6;
        const int lane = t & 63;
        const int lr = lane & 15;
        const int lk = (lane >> 4) * 8;
        const int crow = (lane >> 4) * 4;
        const int ccol = lane & 15;

        s16x8 a[8];
#pragma unroll
        for (int kk = 0; kk < 8; ++kk)       // hoist A-frags: reused by all n-tiles
            a[kk] = *reinterpret_cast<const s16x8*>(&aggl[lr][kk * 32 + lk]);

        s16x8 b[2][8];
#define LOADB(buf, nt)                                                      \
        {                                                                   \
            _Pragma("unroll")                                               \
            for (int kk = 0; kk < 8; ++kk)                                  \
                b[buf][kk] = *reinterpret_cast<const s16x8*>(               \
                    &wb[(size_t)(wv * 256 + (nt) * 16 + lr) * DD + kk * 32 + lk]); \
        }
        LOADB(0, 0)
#pragma unroll
        for (int nt = 0; nt < 16; ++nt) {
            int cur = nt & 1;
            if (nt < 15) LOADB(cur ^ 1, nt + 1)
            f32x4 acc = {};
#pragma unroll
            for (int kk = 0; kk < 8; ++kk)
                acc = __builtin_amdgcn_mfma_f32_16x16x32_bf16(a[kk], b[cur][kk],
                                                              acc, 0, 0, 0);
            int n0 = wv * 256 + nt * 16;
#pragma unroll
            for (int r = 0; r < 4; ++r)
                C[(size_t)(row0 + crow + r) * NOUT + n0 + ccol] = acc[r];
        }
#undef LOADB
    }
}

extern "C" void kernel_launch(void* const* d_in, const int* in_sizes, int n_in,
                              void* d_out, int out_size, void* d_ws, size_t ws_size,
                              hipStream_t stream) {
    const float* x  = (const float*)d_in[0];
    const float* lw = (const float*)d_in[1];   // [H][D][D] == [2048][256] row-major
    const int*   ei = (const int*)d_in[4];
    float* out = (float*)d_out;

    char* ws = (char*)d_ws;
    unsigned int* mask   = (unsigned int*)ws;
    float*        colsum = (float*)(ws + OFF_COLSUM);
    short*        lwb    = (short*)(ws + OFF_LWB);

    // edge_index delivered as int32 (2E elements) vs raw int64 low words
    int stride = (in_sizes[4] == 2 * EE) ? 1 : 2;

    init_k<<<513 + 512, 256, 0, stream>>>(lw, lwb, (float4*)ws);
    edges_colsum_k<<<512 + 64, 256, 0, stream>>>(ei, stride, mask, x, colsum);
    mega_k<<<NB3, 512, 0, stream>>>(x, mask, colsum, lwb, out);
}

// Round 8
// 40.941 us; speedup vs baseline: 4.8561x; 1.5569x over previous
//
#include <hip/hip_runtime.h>
#include <hip/hip_bf16.h>

// GATLayer, scalar attention => uniform 1/deg over DISTINCT neighbors.
//   out[n, h*D+d] = sum_k W[h,d,k] * agg_x[n,k]
//   agg_x[n,:]    = mean_{j in distinct nbr(n)} x[j,:]  (mean over all N if deg==0)
// 4 launches: init (zero+cvtW) | edges+colsum | aggregate | LDS-staged MFMA GEMM.
// R7 lesson: M=16 fused panels re-read W 8x (256MB L2) -> classic 128x128 tiling.

constexpr int NN = 4096;          // nodes
constexpr int DD = 256;           // channels
constexpr int EE = 131072;        // edges
constexpr int MW = NN / 32;       // 128 mask words per row
constexpr int NOUT = 2048;        // H*D
constexpr int LCAP = 256;         // neighbor cap (deg ~ Poisson(32), max ~70)

// ws layout: mask (2 MB) | colsum (1 KB) | aggb (2 MB bf16) | lwb (1 MB bf16)
constexpr size_t OFF_COLSUM = (size_t)NN * MW * 4;
constexpr size_t OFF_AGGB   = OFF_COLSUM + DD * 4;
constexpr size_t OFF_LWB    = OFF_AGGB + (size_t)NN * DD * 2;
constexpr int ZERO_F4 = (int)(OFF_AGGB / 16);        // zero mask+colsum

typedef __attribute__((ext_vector_type(4))) float f32x4;
typedef __attribute__((ext_vector_type(8))) short s16x8;

__device__ inline short f2bf(float f) {
    __hip_bfloat16 h = __float2bfloat16(f);
    return *reinterpret_cast<short*>(&h);
}

// ---- launch 1: zero {mask, colsum}; convert W fp32->bf16 ----
__global__ __launch_bounds__(256) void init_k(const float* __restrict__ w,
                                              short* __restrict__ wb,
                                              float4* __restrict__ zbase) {
    int b = blockIdx.x, t = threadIdx.x;
    if (b < 513) {
        int idx = b * 256 + t;
        if (idx < ZERO_F4) zbase[idx] = make_float4(0.f, 0.f, 0.f, 0.f);
    } else {
        int i = (b - 513) * 256 + t;                 // 131072 float4 = whole W
        float4 v = reinterpret_cast<const float4*>(w)[i];
        short4 o;
        o.x = f2bf(v.x); o.y = f2bf(v.y); o.z = f2bf(v.z); o.w = f2bf(v.w);
        reinterpret_cast<short4*>(wb)[i] = o;
    }
}

// ---- launch 2: edge scatter into bitmask; colsum of x (deg==0 fallback) ----
__global__ __launch_bounds__(256) void edges_k(
        const int* __restrict__ ei, int stride, unsigned int* __restrict__ mask,
        const float* __restrict__ x, float* __restrict__ colsum) {
    int b = blockIdx.x, t = threadIdx.x;
    if (b < 512) {                                   // 512*256 = 131072 edges
        int e = b * 256 + t;
        int u = ei[(size_t)e * stride];              // src (row of adj)
        int v = ei[((size_t)EE + e) * stride];       // dst (col of adj)
        atomicOr(&mask[(size_t)u * MW + (v >> 5)], 1u << (v & 31));
    } else {                                         // 64 blocks x 64 rows
        int r0 = (b - 512) * 64;
        float acc = 0.f;
        for (int r = 0; r < 64; ++r) acc += x[(size_t)(r0 + r) * DD + t];
        atomicAdd(&colsum[t], acc);
    }
}

// ---- launch 3: neighbor mean, 4 rows/block (1024 blocks = 4/CU), wave per row ----
__global__ __launch_bounds__(256) void agg_k(
        const float* __restrict__ x, const unsigned int* __restrict__ mask,
        const float* __restrict__ colsum, short* __restrict__ aggb) {
    __shared__ int nbr[4][LCAP];         // 4 KB
    __shared__ int cnt[4];
    const int t = threadIdx.x;
    const int r = t >> 6;                // wave = row slot
    const int lane = t & 63;
    const int row = blockIdx.x * 4 + r;

    if (lane == 0) cnt[r] = 0;
    __syncthreads();
    // compaction: 64 lanes x 2 words per row
    const unsigned int* mr = &mask[(size_t)row * MW];
#pragma unroll
    for (int j = 0; j < 2; ++j) {
        unsigned int m = mr[lane * 2 + j];
        while (m) {
            int b = __ffs(m) - 1;
            m &= m - 1;
            int idx = atomicAdd(&cnt[r], 1);
            if (idx < LCAP) nbr[r][idx] = (lane * 2 + j) * 32 + b;
        }
    }
    __syncthreads();
    const int deg = min(cnt[r], LCAP);
    const int c4 = lane << 2;            // 4 channels/lane -> 64 lanes = full row

    float4 acc = make_float4(0.f, 0.f, 0.f, 0.f);
    for (int q0 = 0; q0 < deg; q0 += 4) {            // 4 loads in flight
        int nn[4];
        float4 v[4];
#pragma unroll
        for (int j = 0; j < 4; ++j)
            nn[j] = nbr[r][(q0 + j < deg) ? q0 + j : q0];
#pragma unroll
        for (int j = 0; j < 4; ++j)
            v[j] = *reinterpret_cast<const float4*>(&x[(size_t)nn[j] * DD + c4]);
#pragma unroll
        for (int j = 0; j < 4; ++j)
            if (q0 + j < deg) {
                acc.x += v[j].x; acc.y += v[j].y;
                acc.z += v[j].z; acc.w += v[j].w;
            }
    }
    float4 res;
    if (deg > 0) {
        float inv = 1.f / (float)deg;
        res = make_float4(acc.x * inv, acc.y * inv, acc.z * inv, acc.w * inv);
    } else {
        float4 cs = *reinterpret_cast<const float4*>(&colsum[c4]);
        float inv = 1.f / (float)NN;
        res = make_float4(cs.x * inv, cs.y * inv, cs.z * inv, cs.w * inv);
    }
    short4 o;
    o.x = f2bf(res.x); o.y = f2bf(res.y); o.z = f2bf(res.z); o.w = f2bf(res.w);
    *reinterpret_cast<short4*>(&aggb[(size_t)row * DD + c4]) = o;
}

// ---- launch 4: MFMA GEMM  C[4096][2048] = aggb[4096][256] * lwb[2048][256]^T ----
// 128x128 tile, BK=32, double-buffered padded LDS, reg-staged (write-early,
// load-2-ahead), one barrier per K-step. 4 waves (2x2), 64x64 per wave.
constexpr int BK = 32;
constexpr int PADK = 40;                 // 80B row stride: 2 lanes/bank on b128

__global__ __launch_bounds__(256, 2) void gemm_k(
        const short* __restrict__ A, const short* __restrict__ B,
        float* __restrict__ C) {
    __shared__ short As[2][128][PADK];   // 2 x 10 KB
    __shared__ short Bs[2][128][PADK];   // 2 x 10 KB
    const int t = threadIdx.x;
    const int lane = t & 63;
    const int wv = t >> 6;
    const int wr = wv >> 1, wc = wv & 1;
    const int m0 = blockIdx.y * 128;
    const int n0 = blockIdx.x * 128;
    const int lr = lane & 15;
    const int lk = (lane >> 4) * 8;
    // staging coords: thread t covers (row = t/4, kcol = (t&3)*8) and row+64
    const int srow = t >> 2;
    const int skc = (t & 3) * 8;

    f32x4 acc[4][4] = {};
    s16x8 ra0, ra1, rb0, rb1;

#define LOADG(k0)                                                           \
    {                                                                       \
        ra0 = *reinterpret_cast<const s16x8*>(&A[(size_t)(m0 + srow) * DD + (k0) + skc]);      \
        ra1 = *reinterpret_cast<const s16x8*>(&A[(size_t)(m0 + 64 + srow) * DD + (k0) + skc]); \
        rb0 = *reinterpret_cast<const s16x8*>(&B[(size_t)(n0 + srow) * DD + (k0) + skc]);      \
        rb1 = *reinterpret_cast<const s16x8*>(&B[(size_t)(n0 + 64 + srow) * DD + (k0) + skc]); \
    }
#define WRITEL(buf)                                                         \
    {                                                                       \
        *reinterpret_cast<s16x8*>(&As[buf][srow][skc]) = ra0;               \
        *reinterpret_cast<s16x8*>(&As[buf][srow + 64][skc]) = ra1;          \
        *reinterpret_cast<s16x8*>(&Bs[buf][srow][skc]) = rb0;               \
        *reinterpret_cast<s16x8*>(&Bs[buf][srow + 64][skc]) = rb1;          \
    }

    LOADG(0)
    WRITEL(0)
    __syncthreads();
    LOADG(BK)                            // tile 1 in regs

#pragma unroll
    for (int k = 0; k < 8; ++k) {
        const int cur = k & 1;
        if (k < 7) WRITEL(cur ^ 1)       // write tile k+1 (regs loaded an iter ago)
        s16x8 a[4], b[4];
#pragma unroll
        for (int i = 0; i < 4; ++i)
            a[i] = *reinterpret_cast<const s16x8*>(&As[cur][wr * 64 + i * 16 + lr][lk]);
#pragma unroll
        for (int j = 0; j < 4; ++j)
            b[j] = *reinterpret_cast<const s16x8*>(&Bs[cur][wc * 64 + j * 16 + lr][lk]);
        if (k < 6) LOADG((k + 2) * BK)   // issue loads 2 tiles ahead
#pragma unroll
        for (int i = 0; i < 4; ++i)
#pragma unroll
            for (int j = 0; j < 4; ++j)
                acc[i][j] = __builtin_amdgcn_mfma_f32_16x16x32_bf16(
                    a[i], b[j], acc[i][j], 0, 0, 0);
        __syncthreads();                 // all reads of buf[cur] done; writes visible
    }
#undef LOADG
#undef WRITEL

    // C/D layout: col = lane&15, row = (lane>>4)*4 + reg
    const int crow = (lane >> 4) * 4;
    const int ccol = lane & 15;
#pragma unroll
    for (int i = 0; i < 4; ++i)
#pragma unroll
        for (int j = 0; j < 4; ++j)
#pragma unroll
            for (int r = 0; r < 4; ++r)
                C[(size_t)(m0 + wr * 64 + i * 16 + crow + r) * NOUT
                  + n0 + wc * 64 + j * 16 + ccol] = acc[i][j][r];
}

extern "C" void kernel_launch(void* const* d_in, const int* in_sizes, int n_in,
                              void* d_out, int out_size, void* d_ws, size_t ws_size,
                              hipStream_t stream) {
    const float* x  = (const float*)d_in[0];
    const float* lw = (const float*)d_in[1];   // [H][D][D] == [2048][256] row-major
    const int*   ei = (const int*)d_in[4];
    float* out = (float*)d_out;

    char* ws = (char*)d_ws;
    unsigned int* mask   = (unsigned int*)ws;
    float*        colsum = (float*)(ws + OFF_COLSUM);
    short*        aggb   = (short*)(ws + OFF_AGGB);
    short*        lwb    = (short*)(ws + OFF_LWB);

    // edge_index delivered as int32 (2E elements) vs raw int64 low words
    int stride = (in_sizes[4] == 2 * EE) ? 1 : 2;

    init_k<<<513 + 512, 256, 0, stream>>>(lw, lwb, (float4*)ws);
    edges_k<<<512 + 64, 256, 0, stream>>>(ei, stride, mask, x, colsum);
    agg_k<<<NN / 4, 256, 0, stream>>>(x, mask, colsum, aggb);

    dim3 ggrid(NOUT / 128, NN / 128);    // (16, 32) = 512 blocks
    gemm_k<<<ggrid, 256, 0, stream>>>(aggb, lwb, out);
}